// Round 1
// baseline (319.987 us; speedup 1.0000x reference)
//
#include <hip/hip_runtime.h>
#include <hip/hip_bf16.h>

// tanh(X @ W^T + b): M=131072 (16*8192), N=K=256, fp32 in/out.
// Strategy: bf16 MFMA (16x16x32), W pre-converted to bf16 in d_ws,
// A-fragments converted fp32->bf16 in-register. Memory-bound target ~43us.

#define HIDDEN 256
#define M_TOTAL (16 * 8192)

using bf16x8 = __attribute__((ext_vector_type(8))) __bf16;
using f32x4  = __attribute__((ext_vector_type(4))) float;

__global__ __launch_bounds__(256) void wconv_kernel(const float* __restrict__ W,
                                                    __bf16* __restrict__ Wb, int n) {
    int i = blockIdx.x * 256 + threadIdx.x;
    if (i < n) Wb[i] = (__bf16)W[i];
}

__global__ __launch_bounds__(256) void rotor_kernel(const float* __restrict__ X,
                                                    const __bf16* __restrict__ Wb,
                                                    const float* __restrict__ bias,
                                                    float* __restrict__ Y) {
    const int wave = threadIdx.x >> 6;   // 0..3 -> 64-col slice of N
    const int lane = threadIdx.x & 63;
    const int q    = lane >> 4;          // quad 0..3
    const int lr   = lane & 15;

    const int row0  = blockIdx.x * 32;   // 32 rows per block
    const int nbase = wave * 64;

    f32x4 acc[2][4];
#pragma unroll
    for (int m = 0; m < 2; ++m)
#pragma unroll
        for (int t = 0; t < 4; ++t)
            acc[m][t] = (f32x4){0.f, 0.f, 0.f, 0.f};

    // A-fragment base: row (row0+lr [+16]), k offset q*8  (32B aligned)
    const float* xp0 = X + (size_t)(row0 + lr) * HIDDEN + q * 8;
    const float* xp1 = xp0 + 16 * HIDDEN;
    // B-fragment base: W row (nbase + t*16 + lr), k offset q*8 (16B aligned)
    const __bf16* wp = Wb + (size_t)(nbase + lr) * HIDDEN + q * 8;

#pragma unroll
    for (int kc = 0; kc < HIDDEN; kc += 32) {
        float4 a0lo = *(const float4*)(xp0 + kc);
        float4 a0hi = *(const float4*)(xp0 + kc + 4);
        float4 a1lo = *(const float4*)(xp1 + kc);
        float4 a1hi = *(const float4*)(xp1 + kc + 4);

        bf16x8 a0, a1;
        a0[0] = (__bf16)a0lo.x; a0[1] = (__bf16)a0lo.y;
        a0[2] = (__bf16)a0lo.z; a0[3] = (__bf16)a0lo.w;
        a0[4] = (__bf16)a0hi.x; a0[5] = (__bf16)a0hi.y;
        a0[6] = (__bf16)a0hi.z; a0[7] = (__bf16)a0hi.w;
        a1[0] = (__bf16)a1lo.x; a1[1] = (__bf16)a1lo.y;
        a1[2] = (__bf16)a1lo.z; a1[3] = (__bf16)a1lo.w;
        a1[4] = (__bf16)a1hi.x; a1[5] = (__bf16)a1hi.y;
        a1[6] = (__bf16)a1hi.z; a1[7] = (__bf16)a1hi.w;

        bf16x8 b0 = *(const bf16x8*)(wp + kc);
        bf16x8 b1 = *(const bf16x8*)(wp + kc + 16 * HIDDEN);
        bf16x8 b2 = *(const bf16x8*)(wp + kc + 32 * HIDDEN);
        bf16x8 b3 = *(const bf16x8*)(wp + kc + 48 * HIDDEN);

        acc[0][0] = __builtin_amdgcn_mfma_f32_16x16x32_bf16(a0, b0, acc[0][0], 0, 0, 0);
        acc[0][1] = __builtin_amdgcn_mfma_f32_16x16x32_bf16(a0, b1, acc[0][1], 0, 0, 0);
        acc[0][2] = __builtin_amdgcn_mfma_f32_16x16x32_bf16(a0, b2, acc[0][2], 0, 0, 0);
        acc[0][3] = __builtin_amdgcn_mfma_f32_16x16x32_bf16(a0, b3, acc[0][3], 0, 0, 0);
        acc[1][0] = __builtin_amdgcn_mfma_f32_16x16x32_bf16(a1, b0, acc[1][0], 0, 0, 0);
        acc[1][1] = __builtin_amdgcn_mfma_f32_16x16x32_bf16(a1, b1, acc[1][1], 0, 0, 0);
        acc[1][2] = __builtin_amdgcn_mfma_f32_16x16x32_bf16(a1, b2, acc[1][2], 0, 0, 0);
        acc[1][3] = __builtin_amdgcn_mfma_f32_16x16x32_bf16(a1, b3, acc[1][3], 0, 0, 0);
    }

    // Epilogue: C/D layout col=lane&15, row=(lane>>4)*4+reg  [m89-verified]
#pragma unroll
    for (int ms = 0; ms < 2; ++ms) {
#pragma unroll
        for (int t = 0; t < 4; ++t) {
            const int col = nbase + t * 16 + lr;
            const float bv = bias[col];
#pragma unroll
            for (int r = 0; r < 4; ++r) {
                const int row = row0 + ms * 16 + q * 4 + r;
                float z = acc[ms][t][r] + bv;
                z = fminf(fmaxf(z, -10.f), 10.f);      // tanh(+/-10)==+/-1 in fp32
                const float e2 = __expf(2.0f * z);
                const float o  = __fdividef(e2 - 1.0f, e2 + 1.0f);
                Y[(size_t)row * HIDDEN + col] = o;
            }
        }
    }
}

extern "C" void kernel_launch(void* const* d_in, const int* in_sizes, int n_in,
                              void* d_out, int out_size, void* d_ws, size_t ws_size,
                              hipStream_t stream) {
    const float* X    = (const float*)d_in[0];
    const float* W    = (const float*)d_in[1];
    const float* bias = (const float*)d_in[2];
    float* Y          = (float*)d_out;
    __bf16* Wb        = (__bf16*)d_ws;   // 256*256 bf16 = 128 KB

    wconv_kernel<<<dim3(HIDDEN * HIDDEN / 256), dim3(256), 0, stream>>>(W, Wb, HIDDEN * HIDDEN);
    rotor_kernel<<<dim3(M_TOTAL / 32), dim3(256), 0, stream>>>(X, Wb, bias, Y);
}

// Round 2
// 318.367 us; speedup vs baseline: 1.0051x; 1.0051x over previous
//
#include <hip/hip_runtime.h>
#include <hip/hip_bf16.h>

// tanh(X @ W^T + b): M=131072, N=K=256, fp32 in/out.
// R2: LDS-staged, coalesced loads, double-buffered BK=32, bf16 MFMA 16x16x32.
// Block tile: 128 rows x 64 cols, 256 threads (4 waves x 32 rows).
// sW (64x256 bf16, stride 264) loaded once per block; sX double-buffered
// (128x32 bf16, stride 40). Pads make all b128 LDS ops bank-uniform.

#define HIDDEN 256
#define M_TOTAL (16 * 8192)
#define BM 128
#define BN 64
#define BK 32
#define SWS 264   // sW row stride, bf16 elements (528 B)
#define SXS 40    // sX row stride, bf16 elements (80 B)

using bf16x8 = __attribute__((ext_vector_type(8))) __bf16;
using bf16x4 = __attribute__((ext_vector_type(4))) __bf16;
using f32x4  = __attribute__((ext_vector_type(4))) float;

__device__ __forceinline__ bf16x4 cvt4(float4 v) {
    bf16x4 r;
    r[0] = (__bf16)v.x; r[1] = (__bf16)v.y;
    r[2] = (__bf16)v.z; r[3] = (__bf16)v.w;
    return r;
}

__global__ __launch_bounds__(256) void rotor_kernel(const float* __restrict__ X,
                                                    const float* __restrict__ W,
                                                    const float* __restrict__ bias,
                                                    float* __restrict__ Y) {
    __shared__ __align__(16) __bf16 lds[64 * SWS + 2 * BM * SXS];
    __bf16* sW = lds;                 // 64 x SWS
    __bf16* sX = lds + 64 * SWS;      // 2 buffers x BM x SXS

    const int tid  = threadIdx.x;
    const int wave = tid >> 6, lane = tid & 63;
    const int q = lane >> 4, lr = lane & 15;

    // XCD-aware swizzle: all 4 n-slices of one row-block land on one XCD
    const int g   = blockIdx.x;
    const int x8  = g & 7;
    const int h   = g >> 3;
    const int nb  = h & 3;
    const int mb  = (h >> 2) * 8 + x8;
    const int row0 = mb * BM;
    const int nbg  = nb * BN;

    // ---- stage W slice (fp32 -> bf16) into padded LDS, once ----
    {
        const int wrow = tid >> 2;          // 0..63 (col index within slice)
        const int wq   = tid & 3;           // quarter of the K=256 row
        const float* wsrc = W + (size_t)(nbg + wrow) * HIDDEN + wq * 64;
        __bf16* wdst = sW + wrow * SWS + wq * 64;
#pragma unroll
        for (int j = 0; j < 8; ++j) {
            float4 lo = *(const float4*)(wsrc + j * 8);
            float4 hi = *(const float4*)(wsrc + j * 8 + 4);
            bf16x8 v;
            v[0] = (__bf16)lo.x; v[1] = (__bf16)lo.y; v[2] = (__bf16)lo.z; v[3] = (__bf16)lo.w;
            v[4] = (__bf16)hi.x; v[5] = (__bf16)hi.y; v[6] = (__bf16)hi.z; v[7] = (__bf16)hi.w;
            *(bf16x8*)(wdst + j * 8) = v;
        }
    }

    // ---- X staging addresses: thread t, load j covers row j*32 + t/8, cols (t%8)*4 ----
    const int xrow = tid >> 3;              // 0..31
    const int xcol = (tid & 7) * 4;         // float offset within BK
    const float* xbase = X + (size_t)(row0 + xrow) * HIDDEN + xcol;
    __bf16* xdst = sX + xrow * SXS + xcol;

    float4 xr[4];
    // prefetch chunk 0 and stage into buffer 0
#pragma unroll
    for (int j = 0; j < 4; ++j)
        xr[j] = *(const float4*)(xbase + (size_t)j * 32 * HIDDEN);
#pragma unroll
    for (int j = 0; j < 4; ++j)
        *(bf16x4*)(xdst + j * 32 * SXS) = cvt4(xr[j]);

    __syncthreads();

    // ---- fragment base pointers ----
    const __bf16* aptr = sX + (wave * 32 + lr) * SXS + q * 8;   // + m*16*SXS + buf
    const __bf16* bptr = sW + lr * SWS + q * 8;                  // + t*16*SWS + c*BK

    f32x4 acc[2][4];
#pragma unroll
    for (int m = 0; m < 2; ++m)
#pragma unroll
        for (int t = 0; t < 4; ++t)
            acc[m][t] = (f32x4){0.f, 0.f, 0.f, 0.f};

#pragma unroll
    for (int c = 0; c < 8; ++c) {
        // issue next chunk's global loads before compute (latency overlap)
        if (c < 7) {
#pragma unroll
            for (int j = 0; j < 4; ++j)
                xr[j] = *(const float4*)(xbase + (size_t)j * 32 * HIDDEN + (c + 1) * BK);
        }

        const __bf16* ab = aptr + (c & 1) * BM * SXS;
        bf16x8 a0 = *(const bf16x8*)(ab);
        bf16x8 a1 = *(const bf16x8*)(ab + 16 * SXS);

        const __bf16* bb = bptr + c * BK;
        bf16x8 b0 = *(const bf16x8*)(bb);
        bf16x8 b1 = *(const bf16x8*)(bb + 16 * SWS);
        bf16x8 b2 = *(const bf16x8*)(bb + 32 * SWS);
        bf16x8 b3 = *(const bf16x8*)(bb + 48 * SWS);

        acc[0][0] = __builtin_amdgcn_mfma_f32_16x16x32_bf16(a0, b0, acc[0][0], 0, 0, 0);
        acc[0][1] = __builtin_amdgcn_mfma_f32_16x16x32_bf16(a0, b1, acc[0][1], 0, 0, 0);
        acc[0][2] = __builtin_amdgcn_mfma_f32_16x16x32_bf16(a0, b2, acc[0][2], 0, 0, 0);
        acc[0][3] = __builtin_amdgcn_mfma_f32_16x16x32_bf16(a0, b3, acc[0][3], 0, 0, 0);
        acc[1][0] = __builtin_amdgcn_mfma_f32_16x16x32_bf16(a1, b0, acc[1][0], 0, 0, 0);
        acc[1][1] = __builtin_amdgcn_mfma_f32_16x16x32_bf16(a1, b1, acc[1][1], 0, 0, 0);
        acc[1][2] = __builtin_amdgcn_mfma_f32_16x16x32_bf16(a1, b2, acc[1][2], 0, 0, 0);
        acc[1][3] = __builtin_amdgcn_mfma_f32_16x16x32_bf16(a1, b3, acc[1][3], 0, 0, 0);

        if (c < 7) {
            // write next chunk into the other buffer, then sync
#pragma unroll
            for (int j = 0; j < 4; ++j)
                *(bf16x4*)(xdst + ((c + 1) & 1) * BM * SXS + j * 32 * SXS) = cvt4(xr[j]);
            __syncthreads();
        }
    }

    // ---- epilogue: bias + tanh, C/D layout col=lane&15, row=(lane>>4)*4+reg ----
#pragma unroll
    for (int m = 0; m < 2; ++m) {
#pragma unroll
        for (int t = 0; t < 4; ++t) {
            const int col = nbg + t * 16 + lr;
            const float bv = bias[col];
#pragma unroll
            for (int r = 0; r < 4; ++r) {
                const int row = row0 + wave * 32 + m * 16 + q * 4 + r;
                float z = acc[m][t][r] + bv;
                z = fminf(fmaxf(z, -10.f), 10.f);
                const float e2 = __expf(2.0f * z);
                Y[(size_t)row * HIDDEN + col] = __fdividef(e2 - 1.0f, e2 + 1.0f);
            }
        }
    }
}

extern "C" void kernel_launch(void* const* d_in, const int* in_sizes, int n_in,
                              void* d_out, int out_size, void* d_ws, size_t ws_size,
                              hipStream_t stream) {
    const float* X    = (const float*)d_in[0];
    const float* W    = (const float*)d_in[1];
    const float* bias = (const float*)d_in[2];
    float* Y          = (float*)d_out;

    rotor_kernel<<<dim3((M_TOTAL / BM) * (HIDDEN / BN)), dim3(256), 0, stream>>>(X, W, bias, Y);
}

// Round 3
// 264.623 us; speedup vs baseline: 1.2092x; 1.2031x over previous
//
#include <hip/hip_runtime.h>
#include <hip/hip_bf16.h>

// tanh(X @ W^T + b): M=131072, N=K=256, fp32 in/out.
// R3: fragment-ordered LDS (conflict-free b128), per-wave private X staging
// (no k-loop barriers), coalesced float4 stores via LDS epilogue shuffle.
// Block = 128 rows x 64 cols, 4 waves x 32 rows. 48 KB LDS -> 3 blocks/CU.

#define HIDDEN 256
#define M_TOTAL (16 * 8192)

using bf16x8 = __attribute__((ext_vector_type(8))) __bf16;
using bf16x4 = __attribute__((ext_vector_type(4))) __bf16;
using f32x4  = __attribute__((ext_vector_type(4))) float;

__device__ __forceinline__ bf16x4 cvt4(float4 v) {
    bf16x4 r;
    r[0] = (__bf16)v.x; r[1] = (__bf16)v.y;
    r[2] = (__bf16)v.z; r[3] = (__bf16)v.w;
    return r;
}

__global__ __launch_bounds__(256, 3) void rotor_kernel(const float* __restrict__ X,
                                                       const float* __restrict__ W,
                                                       const float* __restrict__ bias,
                                                       float* __restrict__ Y) {
    // sW: 32 frags (c=0..7, t=0..3) x 1024 B, fragment order.
    // sX: 4 waves x 2 bufs x 2 frags x 512 elems (16 KB), per-wave private.
    // sO: epilogue output tile, aliased over sW/sX after a barrier.
    __shared__ __align__(16) unsigned char lds_raw[49152];
    __bf16* sW = (__bf16*)lds_raw;
    __bf16* sX = (__bf16*)(lds_raw + 32768);
    float*  sO = (float*)lds_raw;          // per wave: 32 rows x 66 floats = 2112

    const int tid  = threadIdx.x;
    const int wave = tid >> 6, lane = tid & 63;
    const int q = lane >> 4, lr = lane & 15;

    // XCD swizzle: the 4 col-slices of one row-block share an XCD
    const int g   = blockIdx.x;
    const int x8  = g & 7;
    const int h   = g >> 3;
    const int nb  = h & 3;
    const int mb  = (h >> 2) * 8 + x8;
    const int row0 = mb * 128;
    const int nbg  = nb * 64;

    // ---- stage W slice (fp32 -> bf16) into fragment-ordered LDS ----
    {
        const int wr = tid >> 3;           // 0..31
        const int wk = (tid & 7) * 4;      // k offset 0..28
        const int qw = (tid & 7) >> 1;
        const int lo = tid & 1;
#pragma unroll
        for (int j = 0; j < 2; ++j) {
            const int C = j * 32 + wr;     // col within 64-slice
            const float* wsrc = W + (size_t)(nbg + C) * HIDDEN + wk;
            float4 t[8];
#pragma unroll
            for (int kc = 0; kc < 8; ++kc) t[kc] = *(const float4*)(wsrc + kc * 32);
            // frag (kc*4 + C>>4), slot (qw*16 + C&15), half lo
            __bf16* wb = sW + (C >> 4) * 512 + (qw * 16 + (C & 15)) * 8 + lo * 4;
#pragma unroll
            for (int kc = 0; kc < 8; ++kc) *(bf16x4*)(wb + kc * 2048) = cvt4(t[kc]);
        }
    }

    // ---- per-wave private X staging addresses ----
    const int xr8 = lane >> 3;             // 0..7
    const int qx  = (lane & 7) >> 1;
    const int lox = lane & 1;
    const float* xsrc = X + (size_t)(row0 + wave * 32 + xr8) * HIDDEN + (lane & 7) * 4;
    __bf16* xwb = sX + wave * 2048;        // + buf*1024 + sl*512 + slot*8 + lox*4

    float4 xr[4];
#pragma unroll
    for (int j = 0; j < 4; ++j) xr[j] = *(const float4*)(xsrc + (size_t)j * 8 * HIDDEN);
#pragma unroll
    for (int j = 0; j < 4; ++j) {
        const int R = j * 8 + xr8;
        *(bf16x4*)(xwb + (R >> 4) * 512 + (qx * 16 + (R & 15)) * 8 + lox * 4) = cvt4(xr[j]);
    }

    __syncthreads();   // sW visible to all waves (the ONLY pre-epilogue barrier)

    f32x4 acc[2][4];
#pragma unroll
    for (int m = 0; m < 2; ++m)
#pragma unroll
        for (int t = 0; t < 4; ++t)
            acc[m][t] = (f32x4){0.f, 0.f, 0.f, 0.f};

    const __bf16* ard = sX + wave * 2048 + lane * 8;   // + buf*1024 + sl*512
    const __bf16* brd = sW + lane * 8;                 // + (c*4+t)*512

#pragma unroll
    for (int c = 0; c < 8; ++c) {
        if (c < 7) {
#pragma unroll
            for (int j = 0; j < 4; ++j)
                xr[j] = *(const float4*)(xsrc + (size_t)j * 8 * HIDDEN + (c + 1) * 32);
        }
        const int bsel = (c & 1) * 1024;
        bf16x8 a0 = *(const bf16x8*)(ard + bsel);
        bf16x8 a1 = *(const bf16x8*)(ard + bsel + 512);
        bf16x8 b0 = *(const bf16x8*)(brd + (c * 4 + 0) * 512);
        bf16x8 b1 = *(const bf16x8*)(brd + (c * 4 + 1) * 512);
        bf16x8 b2 = *(const bf16x8*)(brd + (c * 4 + 2) * 512);
        bf16x8 b3 = *(const bf16x8*)(brd + (c * 4 + 3) * 512);

        acc[0][0] = __builtin_amdgcn_mfma_f32_16x16x32_bf16(a0, b0, acc[0][0], 0, 0, 0);
        acc[0][1] = __builtin_amdgcn_mfma_f32_16x16x32_bf16(a0, b1, acc[0][1], 0, 0, 0);
        acc[0][2] = __builtin_amdgcn_mfma_f32_16x16x32_bf16(a0, b2, acc[0][2], 0, 0, 0);
        acc[0][3] = __builtin_amdgcn_mfma_f32_16x16x32_bf16(a0, b3, acc[0][3], 0, 0, 0);
        acc[1][0] = __builtin_amdgcn_mfma_f32_16x16x32_bf16(a1, b0, acc[1][0], 0, 0, 0);
        acc[1][1] = __builtin_amdgcn_mfma_f32_16x16x32_bf16(a1, b1, acc[1][1], 0, 0, 0);
        acc[1][2] = __builtin_amdgcn_mfma_f32_16x16x32_bf16(a1, b2, acc[1][2], 0, 0, 0);
        acc[1][3] = __builtin_amdgcn_mfma_f32_16x16x32_bf16(a1, b3, acc[1][3], 0, 0, 0);

        if (c < 7) {
            const int nb2 = ((c + 1) & 1) * 1024;
#pragma unroll
            for (int j = 0; j < 4; ++j) {
                const int R = j * 8 + xr8;
                *(bf16x4*)(xwb + nb2 + (R >> 4) * 512 + (qx * 16 + (R & 15)) * 8 + lox * 4) = cvt4(xr[j]);
            }
        }
    }

    // ---- epilogue: bias + tanh in regs, LDS shuffle, coalesced float4 stores ----
    float bv[4];
#pragma unroll
    for (int t = 0; t < 4; ++t) bv[t] = bias[nbg + t * 16 + lr];

    float ov[2][4][4];
#pragma unroll
    for (int m = 0; m < 2; ++m)
#pragma unroll
        for (int t = 0; t < 4; ++t)
#pragma unroll
            for (int r = 0; r < 4; ++r) {
                float z = acc[m][t][r] + bv[t];
                z = fminf(fmaxf(z, -10.f), 10.f);
                const float e2 = __expf(2.0f * z);
                ov[m][t][r] = __fdividef(e2 - 1.0f, e2 + 1.0f);
            }

    __syncthreads();   // done with sW/sX; safe to alias as sO

    float* so = sO + wave * 2112;          // 32 rows x 66 floats (pad 2)
#pragma unroll
    for (int m = 0; m < 2; ++m)
#pragma unroll
        for (int t = 0; t < 4; ++t)
#pragma unroll
            for (int r = 0; r < 4; ++r)
                so[(m * 16 + q * 4 + r) * 66 + t * 16 + lr] = ov[m][t][r];

    // read row-major, store 8 full 128-B segments per instruction
    float* ybase = Y + (size_t)(row0 + wave * 32) * HIDDEN + nbg;
#pragma unroll
    for (int j = 0; j < 4; ++j) {
#pragma unroll
        for (int hh = 0; hh < 2; ++hh) {
            const int R = j * 8 + xr8;
            float4 v = *(const float4*)(so + R * 66 + hh * 32 + (lane & 7) * 4);
            *(float4*)(ybase + (size_t)R * HIDDEN + hh * 32 + (lane & 7) * 4) = v;
        }
    }
}

extern "C" void kernel_launch(void* const* d_in, const int* in_sizes, int n_in,
                              void* d_out, int out_size, void* d_ws, size_t ws_size,
                              hipStream_t stream) {
    const float* X    = (const float*)d_in[0];
    const float* W    = (const float*)d_in[1];
    const float* bias = (const float*)d_in[2];
    float* Y          = (float*)d_out;

    rotor_kernel<<<dim3((M_TOTAL / 128) * (HIDDEN / 64)), dim3(256), 0, stream>>>(X, W, bias, Y);
}

// Round 4
// 258.771 us; speedup vs baseline: 1.2366x; 1.0226x over previous
//
#include <hip/hip_runtime.h>
#include <hip/hip_bf16.h>

// tanh(X @ W^T + b): M=131072, N=K=256, fp32 in/out.
// R4: W pre-converted to bf16 B-fragment order in d_ws (L2-hot global loads,
// no LDS for W), per-wave private X staging (barrier-free kernel), dual
// distance-1 prefetch, coalesced float4 stores via per-wave LDS shuffle.
// Block = 128 rows x 64 cols, 4 waves x 32 rows, 17 KB LDS, 4 blocks/CU.

#define HIDDEN 256
#define M_TOTAL (16 * 8192)

using bf16x8 = __attribute__((ext_vector_type(8))) __bf16;
using bf16x4 = __attribute__((ext_vector_type(4))) __bf16;
using f32x4  = __attribute__((ext_vector_type(4))) float;

__device__ __forceinline__ bf16x4 cvt4(float4 v) {
    bf16x4 r;
    r[0] = (__bf16)v.x; r[1] = (__bf16)v.y;
    r[2] = (__bf16)v.z; r[3] = (__bf16)v.w;
    return r;
}

// WF[((nb*8 + c)*4 + t)*512 + lane*8 + j] =
//   bf16( W[(nb*64 + t*16 + (lane&15))*256 + c*32 + (lane>>4)*8 + j] )
__global__ __launch_bounds__(256) void wfrag_kernel(const float* __restrict__ W,
                                                    __bf16* __restrict__ WF) {
    const int gid  = blockIdx.x * 256 + threadIdx.x;   // 0..8191
    const int lane = gid & 63;
    const int t    = (gid >> 6) & 3;
    const int c    = (gid >> 8) & 7;
    const int nb   = gid >> 11;
    const int lr = lane & 15, q = lane >> 4;
    const float* src = W + (size_t)(nb * 64 + t * 16 + lr) * HIDDEN + c * 32 + q * 8;
    float4 lo = *(const float4*)src;
    float4 hi = *(const float4*)(src + 4);
    bf16x8 v;
    v[0] = (__bf16)lo.x; v[1] = (__bf16)lo.y; v[2] = (__bf16)lo.z; v[3] = (__bf16)lo.w;
    v[4] = (__bf16)hi.x; v[5] = (__bf16)hi.y; v[6] = (__bf16)hi.z; v[7] = (__bf16)hi.w;
    *(bf16x8*)(WF + (size_t)gid * 8) = v;
}

__global__ __launch_bounds__(256, 4) void rotor_kernel(const float* __restrict__ X,
                                                       const __bf16* __restrict__ WF,
                                                       const float* __restrict__ bias,
                                                       float* __restrict__ Y) {
    // Per-wave private 4352 B: 2 X-buffers (2x2048 B) aliased with
    // epilogue tile (16 rows x 68 floats = 4352 B). No barriers anywhere.
    __shared__ __align__(16) unsigned char lds_raw[4 * 4352];
    unsigned char* my = lds_raw + (threadIdx.x >> 6) * 4352;
    __bf16* sX = (__bf16*)my;
    float*  sO = (float*)my;

    const int lane = threadIdx.x & 63;
    const int wave = threadIdx.x >> 6;
    const int q = lane >> 4, lr = lane & 15;

    // XCD swizzle: 4 nb-siblings of a row-block temporally adjacent (share X via L2/L3)
    const int g   = blockIdx.x;
    const int x8  = g & 7;
    const int h   = g >> 3;
    const int nbi = h & 3;
    const int mb  = (h >> 2) * 8 + x8;
    const int row0 = mb * 128 + wave * 32;
    const int nbg  = nbi * 64;

    // ---- X staging addresses (per-wave private, coalesced 128B x 8 rows) ----
    const int xr8 = lane >> 3, qx = (lane & 7) >> 1, lox = lane & 1;
    const float* xsrc = X + (size_t)(row0 + xr8) * HIDDEN + (lane & 7) * 4;
    int woff[4];
#pragma unroll
    for (int j = 0; j < 4; ++j) {
        const int R = j * 8 + xr8;
        woff[j] = (R >> 4) * 512 + (qx * 16 + (R & 15)) * 8 + lox * 4;
    }

    // ---- B fragments direct from global (L2-hot), lane*16B coalesced ----
    const __bf16* wf = WF + (size_t)nbi * (8 * 4 * 512) + lane * 8;

    float4 xr[4];
    bf16x8 bc[4], bn[4];
#pragma unroll
    for (int j = 0; j < 4; ++j) xr[j] = *(const float4*)(xsrc + (size_t)j * 8 * HIDDEN);
#pragma unroll
    for (int t = 0; t < 4; ++t) bc[t] = *(const bf16x8*)(wf + t * 512);
#pragma unroll
    for (int j = 0; j < 4; ++j) *(bf16x4*)(sX + woff[j]) = cvt4(xr[j]);

    f32x4 acc[2][4];
#pragma unroll
    for (int m = 0; m < 2; ++m)
#pragma unroll
        for (int t = 0; t < 4; ++t)
            acc[m][t] = (f32x4){0.f, 0.f, 0.f, 0.f};

#pragma unroll
    for (int c = 0; c < 8; ++c) {
        if (c < 7) {
#pragma unroll
            for (int j = 0; j < 4; ++j)
                xr[j] = *(const float4*)(xsrc + (size_t)j * 8 * HIDDEN + (c + 1) * 32);
#pragma unroll
            for (int t = 0; t < 4; ++t)
                bn[t] = *(const bf16x8*)(wf + ((c + 1) * 4 + t) * 512);
        }
        const __bf16* ab = sX + (c & 1) * 1024 + lane * 8;
        bf16x8 a0 = *(const bf16x8*)ab;
        bf16x8 a1 = *(const bf16x8*)(ab + 512);

        acc[0][0] = __builtin_amdgcn_mfma_f32_16x16x32_bf16(a0, bc[0], acc[0][0], 0, 0, 0);
        acc[0][1] = __builtin_amdgcn_mfma_f32_16x16x32_bf16(a0, bc[1], acc[0][1], 0, 0, 0);
        acc[0][2] = __builtin_amdgcn_mfma_f32_16x16x32_bf16(a0, bc[2], acc[0][2], 0, 0, 0);
        acc[0][3] = __builtin_amdgcn_mfma_f32_16x16x32_bf16(a0, bc[3], acc[0][3], 0, 0, 0);
        acc[1][0] = __builtin_amdgcn_mfma_f32_16x16x32_bf16(a1, bc[0], acc[1][0], 0, 0, 0);
        acc[1][1] = __builtin_amdgcn_mfma_f32_16x16x32_bf16(a1, bc[1], acc[1][1], 0, 0, 0);
        acc[1][2] = __builtin_amdgcn_mfma_f32_16x16x32_bf16(a1, bc[2], acc[1][2], 0, 0, 0);
        acc[1][3] = __builtin_amdgcn_mfma_f32_16x16x32_bf16(a1, bc[3], acc[1][3], 0, 0, 0);

        if (c < 7) {
#pragma unroll
            for (int j = 0; j < 4; ++j)
                *(bf16x4*)(sX + ((c + 1) & 1) * 1024 + woff[j]) = cvt4(xr[j]);
#pragma unroll
            for (int t = 0; t < 4; ++t) bc[t] = bn[t];
        }
    }

    // ---- epilogue: bias+tanh, per-wave LDS shuffle, coalesced stores ----
    float bv[4];
#pragma unroll
    for (int t = 0; t < 4; ++t) bv[t] = bias[nbg + t * 16 + lr];

    float* yb = Y + (size_t)row0 * HIDDEN + nbg;
#pragma unroll
    for (int m = 0; m < 2; ++m) {
#pragma unroll
        for (int t = 0; t < 4; ++t)
#pragma unroll
            for (int r = 0; r < 4; ++r) {
                float z = acc[m][t][r] + bv[t];
                z = fminf(fmaxf(z, -10.f), 10.f);
                const float e2 = __expf(2.0f * z);
                sO[(q * 4 + r) * 68 + t * 16 + lr] = __fdividef(e2 - 1.0f, e2 + 1.0f);
            }
#pragma unroll
        for (int j = 0; j < 4; ++j) {
            float4 v = *(const float4*)(sO + (j * 4 + q) * 68 + lr * 4);
            *(float4*)(yb + (size_t)(m * 16 + j * 4 + q) * HIDDEN + lr * 4) = v;
        }
    }
}

extern "C" void kernel_launch(void* const* d_in, const int* in_sizes, int n_in,
                              void* d_out, int out_size, void* d_ws, size_t ws_size,
                              hipStream_t stream) {
    const float* X    = (const float*)d_in[0];
    const float* W    = (const float*)d_in[1];
    const float* bias = (const float*)d_in[2];
    float* Y          = (float*)d_out;
    __bf16* WF        = (__bf16*)d_ws;     // 65536 bf16 = 128 KB

    wfrag_kernel<<<dim3(32), dim3(256), 0, stream>>>(W, WF);
    rotor_kernel<<<dim3((M_TOTAL / 128) * (HIDDEN / 64)), dim3(256), 0, stream>>>(X, WF, bias, Y);
}